// Round 1
// baseline (539.435 us; speedup 1.0000x reference)
//
#include <hip/hip_runtime.h>
#include <math.h>

#define D_MODEL 96
#define D_INNER 192
#define DT_RANK 6
#define K4      4
#define BSZ     4
#define HH      128
#define WW      128
#define LL      16384  // HH*WW

__device__ __forceinline__ float softplusf_(float x) {
    return fmaxf(x, 0.0f) + log1pf(expf(-fabsf(x)));
}

// ---------------------------------------------------------------- kernel 1
// z0[b,d,l] = sum_c in_w[d,c] * x[b,c,l] + in_b[d]
__global__ __launch_bounds__(256) void k_inproj(const float* __restrict__ x,
                                                const float* __restrict__ in_w,
                                                const float* __restrict__ in_b,
                                                float* __restrict__ z0) {
    __shared__ float xt[D_MODEL][64];
    const int blk = blockIdx.x;           // 1024 = 4 b * 256 chunks
    const int b  = blk >> 8;
    const int l0 = (blk & 255) << 6;
    const float* xb = x + (size_t)b * D_MODEL * LL;
    for (int i = threadIdx.x; i < D_MODEL * 64; i += 256) {
        int c = i >> 6, p = i & 63;
        xt[c][p] = xb[(size_t)c * LL + l0 + p];
    }
    __syncthreads();
    const int p = threadIdx.x & 63;
    const int g = __builtin_amdgcn_readfirstlane(threadIdx.x >> 6);  // 0..3, wave-uniform
    float* zb = z0 + (size_t)b * D_INNER * LL + l0 + p;
    for (int jb = 0; jb < 12; ++jb) {
        const int d0 = g * 48 + jb * 4;
        float a0 = in_b[d0], a1 = in_b[d0 + 1], a2 = in_b[d0 + 2], a3 = in_b[d0 + 3];
        const float* w0 = in_w + (size_t)d0 * D_MODEL;
        #pragma unroll 8
        for (int c = 0; c < D_MODEL; ++c) {
            float v = xt[c][p];
            a0 = fmaf(w0[c],                v, a0);
            a1 = fmaf(w0[c + D_MODEL],      v, a1);
            a2 = fmaf(w0[c + 2 * D_MODEL],  v, a2);
            a3 = fmaf(w0[c + 3 * D_MODEL],  v, a3);
        }
        zb[(size_t)d0 * LL]       = a0;
        zb[(size_t)(d0 + 1) * LL] = a1;
        zb[(size_t)(d0 + 2) * LL] = a2;
        zb[(size_t)(d0 + 3) * LL] = a3;
    }
}

// ---------------------------------------------------------------- kernel 2
// depthwise 3x3 SAME conv + bias + SiLU -> z (row-major) and zT (transposed)
__global__ __launch_bounds__(256) void k_dwconv(const float* __restrict__ z0,
                                                const float* __restrict__ dw_w,
                                                const float* __restrict__ dw_b,
                                                float* __restrict__ z,
                                                float* __restrict__ zT) {
    __shared__ float tin[34][34];
    __shared__ float tout[32][33];
    const int blk  = blockIdx.x;          // 768*16
    const int tile = blk & 15;
    const int bd   = blk >> 4;            // b*192 + d
    const int d    = bd % D_INNER;
    const int h0 = (tile >> 2) << 5, w0 = (tile & 3) << 5;
    const float* src = z0 + (size_t)bd * LL;
    for (int i = threadIdx.x; i < 34 * 34; i += 256) {
        int r = i / 34, c = i - r * 34;
        int hh = h0 + r - 1, ww = w0 + c - 1;
        float v = 0.0f;
        if (hh >= 0 && hh < HH && ww >= 0 && ww < WW) v = src[hh * WW + ww];
        tin[r][c] = v;
    }
    __syncthreads();
    float wreg[9];
    #pragma unroll
    for (int i = 0; i < 9; ++i) wreg[i] = dw_w[d * 9 + i];
    const float bias = dw_b[d];
    #pragma unroll
    for (int i = 0; i < 4; ++i) {
        int idx = threadIdx.x + i * 256;
        int r = idx >> 5, c = idx & 31;
        float acc = bias;
        #pragma unroll
        for (int ky = 0; ky < 3; ++ky)
            #pragma unroll
            for (int kx = 0; kx < 3; ++kx)
                acc = fmaf(wreg[ky * 3 + kx], tin[r + ky][c + kx], acc);
        acc = acc / (1.0f + expf(-acc));   // x*sigmoid(x)
        tout[r][c] = acc;
        z[(size_t)bd * LL + (h0 + r) * WW + w0 + c] = acc;
    }
    __syncthreads();
    #pragma unroll
    for (int i = 0; i < 4; ++i) {
        int idx = threadIdx.x + i * 256;
        int r = idx >> 5, c = idx & 31;   // r = w-offset, c = h-offset
        zT[(size_t)bd * LL + (w0 + r) * HH + h0 + c] = tout[c][r];
    }
}

// ---------------------------------------------------------------- kernel 3
// x-proj: per position, project 192 -> 8 for two k's.  src is z (row order,
// kA=0,kB=2) or zT (col order, kA=1,kB=3). Outputs indexed by src position.
__global__ __launch_bounds__(256) void k_proj(const float* __restrict__ src,
                                              const float* __restrict__ xpw,  // (4,8,192)
                                              float* __restrict__ dtsr,       // (b,4,6,L)
                                              float* __restrict__ Bs,         // (b,4,L)
                                              float* __restrict__ Cs,         // (b,4,L)
                                              int kA, int kB) {
    __shared__ float zt[D_INNER][64];
    const int blk = blockIdx.x;           // 1024
    const int b  = blk >> 8;
    const int l0 = (blk & 255) << 6;
    const float* sb = src + (size_t)b * D_INNER * LL + l0;
    for (int i = threadIdx.x; i < D_INNER * 64; i += 256) {
        int dd = i >> 6, p = i & 63;
        zt[dd][p] = sb[(size_t)dd * LL + p];
    }
    __syncthreads();
    const int p = threadIdx.x & 63;
    const int g = __builtin_amdgcn_readfirstlane(threadIdx.x >> 6);
    const int k  = (g < 2) ? kA : kB;
    const int e0 = (g & 1) * 4;
    const float* wrow = xpw + (size_t)(k * 8 + e0) * D_INNER;
    float a0 = 0.f, a1 = 0.f, a2 = 0.f, a3 = 0.f;
    #pragma unroll 8
    for (int dd = 0; dd < D_INNER; ++dd) {
        float v = zt[dd][p];
        a0 = fmaf(wrow[dd],               v, a0);
        a1 = fmaf(wrow[dd + D_INNER],     v, a1);
        a2 = fmaf(wrow[dd + 2 * D_INNER], v, a2);
        a3 = fmaf(wrow[dd + 3 * D_INNER], v, a3);
    }
    const int l = l0 + p;
    const size_t dbase = ((size_t)(b * K4 + k) * DT_RANK) * LL;
    if (e0 == 0) {
        dtsr[dbase + 0 * LL + l] = a0;
        dtsr[dbase + 1 * LL + l] = a1;
        dtsr[dbase + 2 * LL + l] = a2;
        dtsr[dbase + 3 * LL + l] = a3;
    } else {
        dtsr[dbase + 4 * LL + l] = a0;
        dtsr[dbase + 5 * LL + l] = a1;
        Bs[(size_t)(b * K4 + k) * LL + l] = a2;
        Cs[(size_t)(b * K4 + k) * LL + l] = a3;
    }
}

// ---------------------------------------------------------------- scan
// One block per (b,d). 8 chunks of 2048 (256 thr x 8 elem). FWD pass stores
// y, BWD pass (opposite direction, other k) adds. Linear-recurrence pairs
// (P,S): h' = P*h + S, composed in traversal order.
template <bool FWD>
__device__ __forceinline__ void scan_dir(const float* __restrict__ u_base,
                                         const float* __restrict__ dtsr_k,
                                         const float* __restrict__ B_k,
                                         const float* __restrict__ C_k,
                                         const float* __restrict__ dtwp,
                                         float dtbv, float Aval, float Dval,
                                         float* __restrict__ dst_base,
                                         float* wPs, float* wSs) {
    const int tid  = threadIdx.x;
    const int lane = tid & 63;
    const int wv   = tid >> 6;
    float w6[6];
    #pragma unroll
    for (int r = 0; r < 6; ++r) w6[r] = dtwp[r];
    float h0 = 0.0f;
    for (int ci = 0; ci < 8; ++ci) {
        const int c  = FWD ? ci : (7 - ci);
        const int l0 = c * 2048 + tid * 8;
        float u[8], del[8], Bv[8], Cv[8];
        {
            float4 t0 = *(const float4*)(u_base + l0);
            float4 t1 = *(const float4*)(u_base + l0 + 4);
            u[0]=t0.x; u[1]=t0.y; u[2]=t0.z; u[3]=t0.w;
            u[4]=t1.x; u[5]=t1.y; u[6]=t1.z; u[7]=t1.w;
        }
        #pragma unroll
        for (int e = 0; e < 8; ++e) del[e] = dtbv;
        #pragma unroll
        for (int r = 0; r < 6; ++r) {
            float4 t0 = *(const float4*)(dtsr_k + (size_t)r * LL + l0);
            float4 t1 = *(const float4*)(dtsr_k + (size_t)r * LL + l0 + 4);
            del[0] = fmaf(w6[r], t0.x, del[0]); del[1] = fmaf(w6[r], t0.y, del[1]);
            del[2] = fmaf(w6[r], t0.z, del[2]); del[3] = fmaf(w6[r], t0.w, del[3]);
            del[4] = fmaf(w6[r], t1.x, del[4]); del[5] = fmaf(w6[r], t1.y, del[5]);
            del[6] = fmaf(w6[r], t1.z, del[6]); del[7] = fmaf(w6[r], t1.w, del[7]);
        }
        {
            float4 t0 = *(const float4*)(B_k + l0);
            float4 t1 = *(const float4*)(B_k + l0 + 4);
            Bv[0]=t0.x; Bv[1]=t0.y; Bv[2]=t0.z; Bv[3]=t0.w;
            Bv[4]=t1.x; Bv[5]=t1.y; Bv[6]=t1.z; Bv[7]=t1.w;
            t0 = *(const float4*)(C_k + l0);
            t1 = *(const float4*)(C_k + l0 + 4);
            Cv[0]=t0.x; Cv[1]=t0.y; Cv[2]=t0.z; Cv[3]=t0.w;
            Cv[4]=t1.x; Cv[5]=t1.y; Cv[6]=t1.z; Cv[7]=t1.w;
        }
        float a[8], bb[8];
        #pragma unroll
        for (int e = 0; e < 8; ++e) {
            float dl = softplusf_(del[e]);
            a[e]  = expf(dl * Aval);
            bb[e] = dl * Bv[e] * u[e];
        }
        // thread-local fold in traversal order
        float P = 1.0f, S = 0.0f;
        if (FWD) {
            #pragma unroll
            for (int e = 0; e < 8; ++e) { S = fmaf(S, a[e], bb[e]); P *= a[e]; }
        } else {
            #pragma unroll
            for (int e = 7; e >= 0; --e) { S = fmaf(S, a[e], bb[e]); P *= a[e]; }
        }
        // wave-level inclusive scan (Hillis-Steele via shfl)
        #pragma unroll
        for (int s = 1; s < 64; s <<= 1) {
            float p2, s2;
            if (FWD) { p2 = __shfl_up(P, s);   s2 = __shfl_up(S, s); }
            else     { p2 = __shfl_down(P, s); s2 = __shfl_down(S, s); }
            const bool act = FWD ? (lane >= s) : (lane + s < 64);
            if (act) { S = fmaf(s2, P, S); P = p2 * P; }
        }
        __syncthreads();  // protect LDS slots from previous chunk's readers
        if ((FWD && lane == 63) || (!FWD && lane == 0)) { wPs[wv] = P; wSs[wv] = S; }
        __syncthreads();
        // wave prefix (earlier-traversed waves)
        float Pw = 1.0f, Sw = 0.0f;
        if (FWD) { for (int w2 = 0; w2 < wv; ++w2)  { Sw = fmaf(Sw, wPs[w2], wSs[w2]); Pw *= wPs[w2]; } }
        else     { for (int w2 = 3; w2 > wv; --w2)  { Sw = fmaf(Sw, wPs[w2], wSs[w2]); Pw *= wPs[w2]; } }
        // lane-exclusive within wave
        float Pex, Sex;
        if (FWD) { Pex = __shfl_up(P, 1);   Sex = __shfl_up(S, 1);   if (lane == 0)  { Pex = 1.0f; Sex = 0.0f; } }
        else     { Pex = __shfl_down(P, 1); Sex = __shfl_down(S, 1); if (lane == 63) { Pex = 1.0f; Sex = 0.0f; } }
        float h = fmaf(Pw, h0, Sw);
        h = fmaf(Pex, h, Sex);
        // chunk total -> carry (identical on all threads)
        float Pt = 1.0f, St = 0.0f;
        if (FWD) { for (int w2 = 0; w2 < 4; ++w2)  { St = fmaf(St, wPs[w2], wSs[w2]); Pt *= wPs[w2]; } }
        else     { for (int w2 = 3; w2 >= 0; --w2) { St = fmaf(St, wPs[w2], wSs[w2]); Pt *= wPs[w2]; } }
        h0 = fmaf(Pt, h0, St);
        // replay with true incoming state
        float y[8];
        if (FWD) {
            #pragma unroll
            for (int e = 0; e < 8; ++e) { h = fmaf(a[e], h, bb[e]); y[e] = fmaf(h, Cv[e], Dval * u[e]); }
        } else {
            #pragma unroll
            for (int e = 7; e >= 0; --e) { h = fmaf(a[e], h, bb[e]); y[e] = fmaf(h, Cv[e], Dval * u[e]); }
        }
        if (FWD) {
            *(float4*)(dst_base + l0)     = make_float4(y[0], y[1], y[2], y[3]);
            *(float4*)(dst_base + l0 + 4) = make_float4(y[4], y[5], y[6], y[7]);
        } else {
            float4 o0 = *(const float4*)(dst_base + l0);
            float4 o1 = *(const float4*)(dst_base + l0 + 4);
            o0.x += y[0]; o0.y += y[1]; o0.z += y[2]; o0.w += y[3];
            o1.x += y[4]; o1.y += y[5]; o1.z += y[6]; o1.w += y[7];
            *(float4*)(dst_base + l0)     = o0;
            *(float4*)(dst_base + l0 + 4) = o1;
        }
    }
}

__global__ __launch_bounds__(256) void k_scan(const float* __restrict__ src,
                                              const float* __restrict__ dtsr,
                                              const float* __restrict__ BsP,
                                              const float* __restrict__ CsP,
                                              const float* __restrict__ dtw,   // (4,192,6)
                                              const float* __restrict__ dtb,   // (4,192)
                                              const float* __restrict__ A_logs,
                                              const float* __restrict__ Ds,
                                              float* __restrict__ dst,
                                              int kF, int kB) {
    __shared__ float wPs[4], wSs[4];
    const int bd = blockIdx.x;                 // b*192 + d
    const int b = bd / D_INNER, d = bd - b * D_INNER;
    const float* u_base = src + (size_t)bd * LL;
    float* dst_base = dst + (size_t)bd * LL;
    {
        const int kd = kF * D_INNER + d;
        scan_dir<true>(u_base,
                       dtsr + ((size_t)(b * K4 + kF) * DT_RANK) * LL,
                       BsP + (size_t)(b * K4 + kF) * LL,
                       CsP + (size_t)(b * K4 + kF) * LL,
                       dtw + (size_t)kd * 6, dtb[kd], -expf(A_logs[kd]), Ds[kd],
                       dst_base, wPs, wSs);
    }
    __syncthreads();
    {
        const int kd = kB * D_INNER + d;
        scan_dir<false>(u_base,
                        dtsr + ((size_t)(b * K4 + kB) * DT_RANK) * LL,
                        BsP + (size_t)(b * K4 + kB) * LL,
                        CsP + (size_t)(b * K4 + kB) * LL,
                        dtw + (size_t)kd * 6, dtb[kd], -expf(A_logs[kd]), Ds[kd],
                        dst_base, wPs, wSs);
    }
}

// ---------------------------------------------------------------- kernel 7
// ym[b,d,h*W+w] += ym2[b,d,w*H+h]
__global__ __launch_bounds__(256) void k_taddT(const float* __restrict__ ym2,
                                               float* __restrict__ ym) {
    __shared__ float t[32][33];
    const int blk  = blockIdx.x;          // 768*16
    const int tile = blk & 15;
    const int bd   = blk >> 4;
    const int h0 = (tile >> 2) << 5, w0 = (tile & 3) << 5;
    const float* s = ym2 + (size_t)bd * LL;
    float* o = ym + (size_t)bd * LL;
    for (int i = threadIdx.x; i < 1024; i += 256) {
        int r = i >> 5, c = i & 31;       // r = w-off, c = h-off
        t[r][c] = s[(w0 + r) * HH + h0 + c];
    }
    __syncthreads();
    for (int i = threadIdx.x; i < 1024; i += 256) {
        int r = i >> 5, c = i & 31;       // r = h-off, c = w-off
        o[(h0 + r) * WW + w0 + c] += t[c][r];
    }
}

// ---------------------------------------------------------------- kernel 8
// per pixel: LayerNorm over 192 channels, then 192->96 projection + bias
__global__ __launch_bounds__(256) void k_lnout(const float* __restrict__ ym,
                                               const float* __restrict__ ln_w,
                                               const float* __restrict__ ln_b,
                                               const float* __restrict__ out_w,  // (96,192)
                                               const float* __restrict__ out_b,
                                               float* __restrict__ out) {
    __shared__ float yt[D_INNER][64];
    __shared__ float red[8][64];
    __shared__ float mu_s[64], rs_s[64];
    const int blk = blockIdx.x;           // 1024
    const int b  = blk >> 8;
    const int l0 = (blk & 255) << 6;
    const float* sb = ym + (size_t)b * D_INNER * LL + l0;
    for (int i = threadIdx.x; i < D_INNER * 64; i += 256) {
        int dd = i >> 6, p = i & 63;
        yt[dd][p] = sb[(size_t)dd * LL + p];
    }
    __syncthreads();
    const int p = threadIdx.x & 63;
    const int q = __builtin_amdgcn_readfirstlane(threadIdx.x >> 6);
    float s1 = 0.f, s2 = 0.f;
    for (int dd = q * 48; dd < q * 48 + 48; ++dd) {
        float v = yt[dd][p];
        s1 += v;
        s2 = fmaf(v, v, s2);
    }
    red[q][p] = s1;
    red[4 + q][p] = s2;
    __syncthreads();
    if (q == 0) {
        float sa = red[0][p] + red[1][p] + red[2][p] + red[3][p];
        float sq = red[4][p] + red[5][p] + red[6][p] + red[7][p];
        float mu = sa * (1.0f / 192.0f);
        float var = sq * (1.0f / 192.0f) - mu * mu;
        mu_s[p] = mu;
        rs_s[p] = rsqrtf(var + 1e-5f);
    }
    __syncthreads();
    for (int i = threadIdx.x; i < D_INNER * 64; i += 256) {
        int dd = i >> 6, pp = i & 63;
        yt[dd][pp] = fmaf((yt[dd][pp] - mu_s[pp]) * rs_s[pp], ln_w[dd], ln_b[dd]);
    }
    __syncthreads();
    float acc[24];
    #pragma unroll
    for (int cb = 0; cb < 24; ++cb) acc[cb] = 0.f;
    const float* wq = out_w + (size_t)q * 24 * D_INNER;
    for (int dd = 0; dd < D_INNER; ++dd) {
        float v = yt[dd][p];
        #pragma unroll
        for (int cb = 0; cb < 24; ++cb)
            acc[cb] = fmaf(wq[(size_t)cb * D_INNER + dd], v, acc[cb]);
    }
    float* ob = out + (size_t)b * D_MODEL * LL + l0 + p;
    #pragma unroll
    for (int cb = 0; cb < 24; ++cb) {
        int cc = q * 24 + cb;
        ob[(size_t)cc * LL] = acc[cb] + out_b[cc];
    }
}

// ----------------------------------------------------------------
extern "C" void kernel_launch(void* const* d_in, const int* in_sizes, int n_in,
                              void* d_out, int out_size, void* d_ws, size_t ws_size,
                              hipStream_t stream) {
    (void)in_sizes; (void)n_in; (void)out_size; (void)ws_size;
    const float* x      = (const float*)d_in[0];
    const float* in_w   = (const float*)d_in[1];
    const float* in_b   = (const float*)d_in[2];
    const float* dw_w   = (const float*)d_in[3];
    const float* dw_b   = (const float*)d_in[4];
    const float* xpw    = (const float*)d_in[5];
    const float* dtw    = (const float*)d_in[6];
    const float* dtb    = (const float*)d_in[7];
    const float* A_logs = (const float*)d_in[8];
    const float* Ds     = (const float*)d_in[9];
    const float* ln_w   = (const float*)d_in[10];
    const float* ln_b   = (const float*)d_in[11];
    const float* out_w  = (const float*)d_in[12];
    const float* out_b  = (const float*)d_in[13];
    float* out = (float*)d_out;

    float* ws = (float*)d_ws;
    const size_t A1 = (size_t)BSZ * D_INNER * LL;       // 12.58M floats
    float* z0   = ws;                                   // later reused as ym
    float* z    = ws + A1;                              // later reused as ym2
    float* zT   = ws + 2 * A1;
    float* dtsr = ws + 3 * A1;                          // (b,4,6,L)
    float* BsP  = dtsr + (size_t)BSZ * K4 * DT_RANK * LL;
    float* CsP  = BsP + (size_t)BSZ * K4 * LL;
    // total ws use: 3*A1 + 2.1M floats ~ 160 MB

    k_inproj<<<1024, 256, 0, stream>>>(x, in_w, in_b, z0);
    k_dwconv<<<BSZ * D_INNER * 16, 256, 0, stream>>>(z0, dw_w, dw_b, z, zT);
    k_proj<<<1024, 256, 0, stream>>>(z,  xpw, dtsr, BsP, CsP, 0, 2);
    k_proj<<<1024, 256, 0, stream>>>(zT, xpw, dtsr, BsP, CsP, 1, 3);
    float* ym  = z0;  // z0 dead after conv
    float* ym2 = z;   // z dead after row-scan
    k_scan<<<BSZ * D_INNER, 256, 0, stream>>>(z,  dtsr, BsP, CsP, dtw, dtb, A_logs, Ds, ym,  0, 2);
    k_scan<<<BSZ * D_INNER, 256, 0, stream>>>(zT, dtsr, BsP, CsP, dtw, dtb, A_logs, Ds, ym2, 1, 3);
    k_taddT<<<BSZ * D_INNER * 16, 256, 0, stream>>>(ym2, ym);
    k_lnout<<<1024, 256, 0, stream>>>(ym, ln_w, ln_b, out_w, out_b, out);
}

// Round 2
// 436.981 us; speedup vs baseline: 1.2345x; 1.2345x over previous
//
#include <hip/hip_runtime.h>
#include <math.h>

#define D_MODEL 96
#define D_INNER 192
#define DT_RANK 6
#define K4      4
#define BSZ     4
#define HH      128
#define WW      128
#define LL      16384  // HH*WW

#define LOG2E 1.4426950408889634f
#define LN2   0.6931471805599453f

#if __has_builtin(__builtin_amdgcn_exp2f)
__device__ __forceinline__ float fexp2_(float x){ return __builtin_amdgcn_exp2f(x); }
#else
__device__ __forceinline__ float fexp2_(float x){ return exp2f(x); }
#endif
#if __has_builtin(__builtin_amdgcn_logf)
__device__ __forceinline__ float flog2_(float x){ return __builtin_amdgcn_logf(x); }
#else
__device__ __forceinline__ float flog2_(float x){ return log2f(x); }
#endif
#if __has_builtin(__builtin_amdgcn_rcpf)
__device__ __forceinline__ float frcp_(float x){ return __builtin_amdgcn_rcpf(x); }
#else
__device__ __forceinline__ float frcp_(float x){ return 1.0f/x; }
#endif

__device__ __forceinline__ float softplus_fast(float x){
    return fmaxf(x, 0.0f) + LN2 * flog2_(1.0f + fexp2_(-LOG2E * fabsf(x)));
}
__device__ __forceinline__ float silu_fast(float x){
    return x * frcp_(1.0f + fexp2_(-LOG2E * x));
}

// ---------------------------------------------------------------- kernel 1
// z0[b,d,l] = sum_c in_w[d,c] * x[b,c,l] + in_b[d]   (8 accums/thread)
__global__ __launch_bounds__(256) void k_inproj(const float* __restrict__ x,
                                                const float* __restrict__ in_w,
                                                const float* __restrict__ in_b,
                                                float* __restrict__ z0) {
    __shared__ float xt[D_MODEL][64];
    const int blk = blockIdx.x;           // 1024 = 4 b * 256 chunks
    const int b  = blk >> 8;
    const int l0 = (blk & 255) << 6;
    const float* xb = x + (size_t)b * D_MODEL * LL;
    for (int i = threadIdx.x; i < D_MODEL * 64; i += 256) {
        int c = i >> 6, p = i & 63;
        xt[c][p] = xb[(size_t)c * LL + l0 + p];
    }
    __syncthreads();
    const int p = threadIdx.x & 63;
    const int g = __builtin_amdgcn_readfirstlane(threadIdx.x >> 6);  // 0..3
    float* zb = z0 + (size_t)b * D_INNER * LL + l0 + p;
    for (int jb = 0; jb < 6; ++jb) {
        const int d0 = g * 48 + jb * 8;
        float acc[8];
        #pragma unroll
        for (int j = 0; j < 8; ++j) acc[j] = in_b[d0 + j];
        const float* w0 = in_w + (size_t)d0 * D_MODEL;
        #pragma unroll 4
        for (int c = 0; c < D_MODEL; ++c) {
            float v = xt[c][p];
            #pragma unroll
            for (int j = 0; j < 8; ++j)
                acc[j] = fmaf(w0[c + j * D_MODEL], v, acc[j]);
        }
        #pragma unroll
        for (int j = 0; j < 8; ++j) zb[(size_t)(d0 + j) * LL] = acc[j];
    }
}

// ---------------------------------------------------------------- kernel 2
// depthwise 3x3 SAME conv + bias + SiLU -> z (row-major) and zT (transposed)
__global__ __launch_bounds__(256) void k_dwconv(const float* __restrict__ z0,
                                                const float* __restrict__ dw_w,
                                                const float* __restrict__ dw_b,
                                                float* __restrict__ z,
                                                float* __restrict__ zT) {
    __shared__ float tin[34][34];
    __shared__ float tout[32][33];
    const int blk  = blockIdx.x;          // 768*16
    const int tile = blk & 15;
    const int bd   = blk >> 4;            // b*192 + d
    const int d    = bd % D_INNER;
    const int h0 = (tile >> 2) << 5, w0 = (tile & 3) << 5;
    const float* src = z0 + (size_t)bd * LL;
    for (int i = threadIdx.x; i < 34 * 34; i += 256) {
        int r = i / 34, c = i - r * 34;
        int hh = h0 + r - 1, ww = w0 + c - 1;
        float v = 0.0f;
        if (hh >= 0 && hh < HH && ww >= 0 && ww < WW) v = src[hh * WW + ww];
        tin[r][c] = v;
    }
    __syncthreads();
    float wreg[9];
    #pragma unroll
    for (int i = 0; i < 9; ++i) wreg[i] = dw_w[d * 9 + i];
    const float bias = dw_b[d];
    #pragma unroll
    for (int i = 0; i < 4; ++i) {
        int idx = threadIdx.x + i * 256;
        int r = idx >> 5, c = idx & 31;
        float acc = bias;
        #pragma unroll
        for (int ky = 0; ky < 3; ++ky)
            #pragma unroll
            for (int kx = 0; kx < 3; ++kx)
                acc = fmaf(wreg[ky * 3 + kx], tin[r + ky][c + kx], acc);
        acc = silu_fast(acc);
        tout[r][c] = acc;
        z[(size_t)bd * LL + (h0 + r) * WW + w0 + c] = acc;
    }
    __syncthreads();
    #pragma unroll
    for (int i = 0; i < 4; ++i) {
        int idx = threadIdx.x + i * 256;
        int r = idx >> 5, c = idx & 31;   // r = w-offset, c = h-offset
        zT[(size_t)bd * LL + (w0 + r) * HH + h0 + c] = tout[c][r];
    }
}

// ---------------------------------------------------------------- kernel 3
// x-proj: per position, project 192 -> 8 for two k's. One dispatch, grid 2048:
// seg0: src z (row order, k=0,2); seg1: src zT (col order, k=1,3).
__global__ __launch_bounds__(256) void k_proj(const float* __restrict__ z,
                                              const float* __restrict__ zT,
                                              const float* __restrict__ xpw,  // (4,8,192)
                                              float* __restrict__ dtsr,       // (b,4,6,L)
                                              float* __restrict__ Bs,         // (b,4,L)
                                              float* __restrict__ Cs) {
    __shared__ float zt[D_INNER][64];
    const int blk = blockIdx.x;           // 2048
    const int seg = blk >> 10;
    const int rest = blk & 1023;
    const int b  = rest >> 8;
    const int l0 = (rest & 255) << 6;
    const int kA = seg ? 1 : 0;
    const int kB = seg ? 3 : 2;
    const float* src = seg ? zT : z;
    const float* sb = src + (size_t)b * D_INNER * LL + l0;
    for (int i = threadIdx.x; i < D_INNER * 64; i += 256) {
        int dd = i >> 6, p = i & 63;
        zt[dd][p] = sb[(size_t)dd * LL + p];
    }
    __syncthreads();
    const int p = threadIdx.x & 63;
    const int g = __builtin_amdgcn_readfirstlane(threadIdx.x >> 6);
    const int k  = (g < 2) ? kA : kB;
    const int e0 = (g & 1) * 4;
    const float* wrow = xpw + (size_t)(k * 8 + e0) * D_INNER;
    float a0 = 0.f, a1 = 0.f, a2 = 0.f, a3 = 0.f;
    #pragma unroll 8
    for (int dd = 0; dd < D_INNER; ++dd) {
        float v = zt[dd][p];
        a0 = fmaf(wrow[dd],               v, a0);
        a1 = fmaf(wrow[dd + D_INNER],     v, a1);
        a2 = fmaf(wrow[dd + 2 * D_INNER], v, a2);
        a3 = fmaf(wrow[dd + 3 * D_INNER], v, a3);
    }
    const int l = l0 + p;
    const size_t dbase = ((size_t)(b * K4 + k) * DT_RANK) * LL;
    if (e0 == 0) {
        dtsr[dbase + 0 * LL + l] = a0;
        dtsr[dbase + 1 * LL + l] = a1;
        dtsr[dbase + 2 * LL + l] = a2;
        dtsr[dbase + 3 * LL + l] = a3;
    } else {
        dtsr[dbase + 4 * LL + l] = a0;
        dtsr[dbase + 5 * LL + l] = a1;
        Bs[(size_t)(b * K4 + k) * LL + l] = a2;
        Cs[(size_t)(b * K4 + k) * LL + l] = a3;
    }
}

// ---------------------------------------------------------------- scan core
// One direction over 16384 elems, 8 chunks of 2048 (256 thr x 8). Linear
// stores always. LDSU: u comes from row-major z via LDS transpose (col order).
template <bool FWD, bool RMW, bool LDSU>
__device__ __forceinline__ void scan_core(const float* __restrict__ u_lin,
                                          const float* __restrict__ u_rm,
                                          const float* __restrict__ dtsr_k,
                                          const float* __restrict__ B_k,
                                          const float* __restrict__ C_k,
                                          const float* __restrict__ w6p,
                                          float dtbv, float A2, float Dval,
                                          float* __restrict__ dst,
                                          float* __restrict__ wPs,
                                          float* __restrict__ wSs,
                                          float* __restrict__ tile) {
    const int tid  = threadIdx.x;
    const int lane = tid & 63;
    const int wv   = tid >> 6;
    float w6[6];
    #pragma unroll
    for (int r = 0; r < 6; ++r) w6[r] = w6p[r];
    float h0 = 0.0f;
    for (int ci = 0; ci < 8; ++ci) {
        const int c  = FWD ? ci : (7 - ci);
        const int l0 = (c << 11) + (tid << 3);
        float u[8];
        if (LDSU) {
            #pragma unroll
            for (int e = 0; e < 8; ++e) {
                int idx = tid + (e << 8);
                int h = idx >> 4, w = idx & 15;
                tile[w * 132 + h] = u_rm[h * WW + (c << 4) + w];
            }
            __syncthreads();
            const int wl = tid >> 4;
            const int hb = (tid & 15) << 3;
            #pragma unroll
            for (int e = 0; e < 8; ++e) u[e] = tile[wl * 132 + hb + e];
        } else {
            float4 t0 = *(const float4*)(u_lin + l0);
            float4 t1 = *(const float4*)(u_lin + l0 + 4);
            u[0]=t0.x; u[1]=t0.y; u[2]=t0.z; u[3]=t0.w;
            u[4]=t1.x; u[5]=t1.y; u[6]=t1.z; u[7]=t1.w;
        }
        float dl[8];
        #pragma unroll
        for (int e = 0; e < 8; ++e) dl[e] = dtbv;
        #pragma unroll
        for (int r = 0; r < 6; ++r) {
            float4 t0 = *(const float4*)(dtsr_k + (size_t)r * LL + l0);
            float4 t1 = *(const float4*)(dtsr_k + (size_t)r * LL + l0 + 4);
            dl[0] = fmaf(w6[r], t0.x, dl[0]); dl[1] = fmaf(w6[r], t0.y, dl[1]);
            dl[2] = fmaf(w6[r], t0.z, dl[2]); dl[3] = fmaf(w6[r], t0.w, dl[3]);
            dl[4] = fmaf(w6[r], t1.x, dl[4]); dl[5] = fmaf(w6[r], t1.y, dl[5]);
            dl[6] = fmaf(w6[r], t1.z, dl[6]); dl[7] = fmaf(w6[r], t1.w, dl[7]);
        }
        float Bv[8], Cv[8];
        {
            float4 t0 = *(const float4*)(B_k + l0);
            float4 t1 = *(const float4*)(B_k + l0 + 4);
            Bv[0]=t0.x; Bv[1]=t0.y; Bv[2]=t0.z; Bv[3]=t0.w;
            Bv[4]=t1.x; Bv[5]=t1.y; Bv[6]=t1.z; Bv[7]=t1.w;
            t0 = *(const float4*)(C_k + l0);
            t1 = *(const float4*)(C_k + l0 + 4);
            Cv[0]=t0.x; Cv[1]=t0.y; Cv[2]=t0.z; Cv[3]=t0.w;
            Cv[4]=t1.x; Cv[5]=t1.y; Cv[6]=t1.z; Cv[7]=t1.w;
        }
        float a[8], bb[8];
        #pragma unroll
        for (int e = 0; e < 8; ++e) {
            float d1 = softplus_fast(dl[e]);
            a[e]  = fexp2_(d1 * A2);
            bb[e] = d1 * Bv[e] * u[e];
        }
        // thread-local fold in traversal order
        float P = 1.0f, S = 0.0f;
        if (FWD) {
            #pragma unroll
            for (int e = 0; e < 8; ++e) { S = fmaf(S, a[e], bb[e]); P *= a[e]; }
        } else {
            #pragma unroll
            for (int e = 7; e >= 0; --e) { S = fmaf(S, a[e], bb[e]); P *= a[e]; }
        }
        // wave-level inclusive scan (Hillis-Steele via shfl)
        #pragma unroll
        for (int s = 1; s < 64; s <<= 1) {
            float p2, s2;
            if (FWD) { p2 = __shfl_up(P, s);   s2 = __shfl_up(S, s); }
            else     { p2 = __shfl_down(P, s); s2 = __shfl_down(S, s); }
            const bool act = FWD ? (lane >= s) : (lane + s < 64);
            if (act) { S = fmaf(s2, P, S); P = p2 * P; }
        }
        __syncthreads();  // protect LDS slots (and LDSU tile) from prev readers
        if ((FWD && lane == 63) || (!FWD && lane == 0)) { wPs[wv] = P; wSs[wv] = S; }
        __syncthreads();
        // wave prefix (earlier-traversed waves)
        float Pw = 1.0f, Sw = 0.0f;
        if (FWD) { for (int w2 = 0; w2 < wv; ++w2)  { Sw = fmaf(Sw, wPs[w2], wSs[w2]); Pw *= wPs[w2]; } }
        else     { for (int w2 = 3; w2 > wv; --w2)  { Sw = fmaf(Sw, wPs[w2], wSs[w2]); Pw *= wPs[w2]; } }
        // lane-exclusive within wave
        float Pex, Sex;
        if (FWD) { Pex = __shfl_up(P, 1);   Sex = __shfl_up(S, 1);   if (lane == 0)  { Pex = 1.0f; Sex = 0.0f; } }
        else     { Pex = __shfl_down(P, 1); Sex = __shfl_down(S, 1); if (lane == 63) { Pex = 1.0f; Sex = 0.0f; } }
        float h = fmaf(Pw, h0, Sw);
        h = fmaf(Pex, h, Sex);
        // chunk total -> carry (identical on all threads)
        float Pt = 1.0f, St = 0.0f;
        if (FWD) { for (int w2 = 0; w2 < 4; ++w2)  { St = fmaf(St, wPs[w2], wSs[w2]); Pt *= wPs[w2]; } }
        else     { for (int w2 = 3; w2 >= 0; --w2) { St = fmaf(St, wPs[w2], wSs[w2]); Pt *= wPs[w2]; } }
        h0 = fmaf(Pt, h0, St);
        // replay with true incoming state
        float y[8];
        if (FWD) {
            #pragma unroll
            for (int e = 0; e < 8; ++e) { h = fmaf(a[e], h, bb[e]); y[e] = fmaf(h, Cv[e], Dval * u[e]); }
        } else {
            #pragma unroll
            for (int e = 7; e >= 0; --e) { h = fmaf(a[e], h, bb[e]); y[e] = fmaf(h, Cv[e], Dval * u[e]); }
        }
        if (!RMW) {
            *(float4*)(dst + l0)     = make_float4(y[0], y[1], y[2], y[3]);
            *(float4*)(dst + l0 + 4) = make_float4(y[4], y[5], y[6], y[7]);
        } else {
            float4 o0 = *(const float4*)(dst + l0);
            float4 o1 = *(const float4*)(dst + l0 + 4);
            o0.x += y[0]; o0.y += y[1]; o0.z += y[2]; o0.w += y[3];
            o1.x += y[4]; o1.y += y[5]; o1.z += y[6]; o1.w += y[7];
            *(float4*)(dst + l0)     = o0;
            *(float4*)(dst + l0 + 4) = o1;
        }
    }
}

// scanA: half0 = fwd-row (k0, store y_r), half1 = bwd-col (k3, store zT in place)
__global__ __launch_bounds__(256) void k_scanA(const float* __restrict__ z,
                                               float* __restrict__ zT,
                                               float* __restrict__ y_r,
                                               const float* __restrict__ dtsr,
                                               const float* __restrict__ Bs,
                                               const float* __restrict__ Cs,
                                               const float* __restrict__ dtw,
                                               const float* __restrict__ dtb,
                                               const float* __restrict__ A_logs,
                                               const float* __restrict__ Ds) {
    __shared__ float wPs[4], wSs[4];
    const int blk = blockIdx.x;           // 1536
    const int half = blk >= 768;
    const int bd = half ? blk - 768 : blk;
    const int b = bd / D_INNER, d = bd - b * D_INNER;
    const int k = half ? 3 : 0;
    const int kd = k * D_INNER + d;
    const float* dk = dtsr + ((size_t)(b * K4 + k) * DT_RANK) * LL;
    const float* Bk = Bs + (size_t)(b * K4 + k) * LL;
    const float* Ck = Cs + (size_t)(b * K4 + k) * LL;
    const float* w6p = dtw + (size_t)kd * 6;
    const float A2 = -expf(A_logs[kd]) * LOG2E;
    if (!half)
        scan_core<true, false, false>(z + (size_t)bd * LL, nullptr, dk, Bk, Ck, w6p,
                                      dtb[kd], A2, Ds[kd], y_r + (size_t)bd * LL,
                                      wPs, wSs, nullptr);
    else
        scan_core<false, false, false>(zT + (size_t)bd * LL, nullptr, dk, Bk, Ck, w6p,
                                       dtb[kd], A2, Ds[kd], zT + (size_t)bd * LL,
                                       wPs, wSs, nullptr);
}

// scanB: half0 = bwd-row (k2, RMW y_r), half1 = fwd-col (k1, u via LDS transpose
// of z, RMW zT which holds col-major y)
__global__ __launch_bounds__(256) void k_scanB(const float* __restrict__ z,
                                               float* __restrict__ zT,
                                               float* __restrict__ y_r,
                                               const float* __restrict__ dtsr,
                                               const float* __restrict__ Bs,
                                               const float* __restrict__ Cs,
                                               const float* __restrict__ dtw,
                                               const float* __restrict__ dtb,
                                               const float* __restrict__ A_logs,
                                               const float* __restrict__ Ds) {
    __shared__ float wPs[4], wSs[4];
    __shared__ float tile[16 * 132];
    const int blk = blockIdx.x;           // 1536
    const int half = blk >= 768;
    const int bd = half ? blk - 768 : blk;
    const int b = bd / D_INNER, d = bd - b * D_INNER;
    const int k = half ? 1 : 2;
    const int kd = k * D_INNER + d;
    const float* dk = dtsr + ((size_t)(b * K4 + k) * DT_RANK) * LL;
    const float* Bk = Bs + (size_t)(b * K4 + k) * LL;
    const float* Ck = Cs + (size_t)(b * K4 + k) * LL;
    const float* w6p = dtw + (size_t)kd * 6;
    const float A2 = -expf(A_logs[kd]) * LOG2E;
    if (!half)
        scan_core<false, true, false>(z + (size_t)bd * LL, nullptr, dk, Bk, Ck, w6p,
                                      dtb[kd], A2, Ds[kd], y_r + (size_t)bd * LL,
                                      wPs, wSs, nullptr);
    else
        scan_core<true, true, true>(nullptr, z + (size_t)bd * LL, dk, Bk, Ck, w6p,
                                    dtb[kd], A2, Ds[kd], zT + (size_t)bd * LL,
                                    wPs, wSs, tile);
}

// ---------------------------------------------------------------- merge
// y_r[b,d,h*W+w] += y_c[b,d,w*H+h]   (y_c lives in zT, col-major)
__global__ __launch_bounds__(256) void k_taddT(const float* __restrict__ ym2,
                                               float* __restrict__ ym) {
    __shared__ float t[32][33];
    const int blk  = blockIdx.x;          // 768*16
    const int tile = blk & 15;
    const int bd   = blk >> 4;
    const int h0 = (tile >> 2) << 5, w0 = (tile & 3) << 5;
    const float* s = ym2 + (size_t)bd * LL;
    float* o = ym + (size_t)bd * LL;
    for (int i = threadIdx.x; i < 1024; i += 256) {
        int r = i >> 5, c = i & 31;       // r = w-off, c = h-off
        t[r][c] = s[(w0 + r) * HH + h0 + c];
    }
    __syncthreads();
    for (int i = threadIdx.x; i < 1024; i += 256) {
        int r = i >> 5, c = i & 31;       // r = h-off, c = w-off
        o[(h0 + r) * WW + w0 + c] += t[c][r];
    }
}

// ---------------------------------------------------------------- kernel 8
// per pixel: LayerNorm over 192 channels, then 192->96 projection + bias
__global__ __launch_bounds__(256) void k_lnout(const float* __restrict__ ym,
                                               const float* __restrict__ ln_w,
                                               const float* __restrict__ ln_b,
                                               const float* __restrict__ out_w,  // (96,192)
                                               const float* __restrict__ out_b,
                                               float* __restrict__ out) {
    __shared__ float yt[D_INNER][64];
    __shared__ float red[8][64];
    __shared__ float mu_s[64], rs_s[64];
    const int blk = blockIdx.x;           // 1024
    const int b  = blk >> 8;
    const int l0 = (blk & 255) << 6;
    const float* sb = ym + (size_t)b * D_INNER * LL + l0;
    for (int i = threadIdx.x; i < D_INNER * 64; i += 256) {
        int dd = i >> 6, p = i & 63;
        yt[dd][p] = sb[(size_t)dd * LL + p];
    }
    __syncthreads();
    const int p = threadIdx.x & 63;
    const int q = __builtin_amdgcn_readfirstlane(threadIdx.x >> 6);
    float s1 = 0.f, s2 = 0.f;
    for (int dd = q * 48; dd < q * 48 + 48; ++dd) {
        float v = yt[dd][p];
        s1 += v;
        s2 = fmaf(v, v, s2);
    }
    red[q][p] = s1;
    red[4 + q][p] = s2;
    __syncthreads();
    if (q == 0) {
        float sa = red[0][p] + red[1][p] + red[2][p] + red[3][p];
        float sq = red[4][p] + red[5][p] + red[6][p] + red[7][p];
        float mu = sa * (1.0f / 192.0f);
        float var = sq * (1.0f / 192.0f) - mu * mu;
        mu_s[p] = mu;
        rs_s[p] = rsqrtf(var + 1e-5f);
    }
    __syncthreads();
    for (int i = threadIdx.x; i < D_INNER * 64; i += 256) {
        int dd = i >> 6, pp = i & 63;
        yt[dd][pp] = fmaf((yt[dd][pp] - mu_s[pp]) * rs_s[pp], ln_w[dd], ln_b[dd]);
    }
    __syncthreads();
    float acc[24];
    #pragma unroll
    for (int cb = 0; cb < 24; ++cb) acc[cb] = 0.f;
    const float* wq = out_w + (size_t)q * 24 * D_INNER;
    for (int dd = 0; dd < D_INNER; ++dd) {
        float v = yt[dd][p];
        #pragma unroll
        for (int cb = 0; cb < 24; ++cb)
            acc[cb] = fmaf(wq[(size_t)cb * D_INNER + dd], v, acc[cb]);
    }
    float* ob = out + (size_t)b * D_MODEL * LL + l0 + p;
    #pragma unroll
    for (int cb = 0; cb < 24; ++cb) {
        int cc = q * 24 + cb;
        ob[(size_t)cc * LL] = acc[cb] + out_b[cc];
    }
}

// ----------------------------------------------------------------
extern "C" void kernel_launch(void* const* d_in, const int* in_sizes, int n_in,
                              void* d_out, int out_size, void* d_ws, size_t ws_size,
                              hipStream_t stream) {
    (void)in_sizes; (void)n_in; (void)out_size; (void)ws_size;
    const float* x      = (const float*)d_in[0];
    const float* in_w   = (const float*)d_in[1];
    const float* in_b   = (const float*)d_in[2];
    const float* dw_w   = (const float*)d_in[3];
    const float* dw_b   = (const float*)d_in[4];
    const float* xpw    = (const float*)d_in[5];
    const float* dtw    = (const float*)d_in[6];
    const float* dtb    = (const float*)d_in[7];
    const float* A_logs = (const float*)d_in[8];
    const float* Ds     = (const float*)d_in[9];
    const float* ln_w   = (const float*)d_in[10];
    const float* ln_b   = (const float*)d_in[11];
    const float* out_w  = (const float*)d_in[12];
    const float* out_b  = (const float*)d_in[13];
    float* out = (float*)d_out;

    float* ws = (float*)d_ws;
    const size_t A1 = (size_t)BSZ * D_INNER * LL;       // 12.58M floats
    float* z0   = ws;                                   // reused as y_r after conv
    float* z    = ws + A1;
    float* zT   = ws + 2 * A1;                          // reused in-place as y_c (col-major)
    float* dtsr = ws + 3 * A1;                          // (b,4,6,L)
    float* BsP  = dtsr + (size_t)BSZ * K4 * DT_RANK * LL;
    float* CsP  = BsP + (size_t)BSZ * K4 * LL;
    // total ws use: 3*A1 + 2.1M floats ~ 159 MB (same as round 1)

    float* y_r = z0;

    k_inproj<<<1024, 256, 0, stream>>>(x, in_w, in_b, z0);
    k_dwconv<<<BSZ * D_INNER * 16, 256, 0, stream>>>(z0, dw_w, dw_b, z, zT);
    k_proj<<<2048, 256, 0, stream>>>(z, zT, xpw, dtsr, BsP, CsP);
    k_scanA<<<1536, 256, 0, stream>>>(z, zT, y_r, dtsr, BsP, CsP, dtw, dtb, A_logs, Ds);
    k_scanB<<<1536, 256, 0, stream>>>(z, zT, y_r, dtsr, BsP, CsP, dtw, dtb, A_logs, Ds);
    k_taddT<<<BSZ * D_INNER * 16, 256, 0, stream>>>(zT, y_r);
    k_lnout<<<1024, 256, 0, stream>>>(y_r, ln_w, ln_b, out_w, out_b, out);
}